// Round 8
// baseline (156.846 us; speedup 1.0000x reference)
//
#include <hip/hip_runtime.h>

#define BB 8
#define NN 2048
#define IND 128
#define OUTD 64
#define ALPHA 0.2f
#define NBLK 512   // k23 grid: 512 blocks x 2 tiles = 1024 tiles of 16 rows

typedef __attribute__((ext_vector_type(8))) short bf16x8;
typedef __attribute__((ext_vector_type(4))) float f32x4;
typedef unsigned int u32;

// LDS-only barrier: does NOT drain vmcnt (global NT stores keep flowing).
__device__ __forceinline__ void bar_lds() {
    asm volatile("s_waitcnt lgkmcnt(0)\n\ts_barrier" ::: "memory");
}

// ---------------- K1: h = x@W -> h_T (bf16 hi/lo, [B][64][2048]), si, sj ----
__global__ __launch_bounds__(256) void k1_hproj(const float* __restrict__ x,
                                                const float* __restrict__ W,
                                                const float* __restrict__ a,
                                                short* __restrict__ hT_hi,
                                                short* __restrict__ hT_lo,
                                                float* __restrict__ si,
                                                float* __restrict__ sj) {
    __shared__ float Wl[IND * OUTD];     // 32 KB
    __shared__ float xl[16][IND];        // 8 KB
    __shared__ float tile[16][OUTD + 1]; // h tile for transpose (pad 65)
    int t = threadIdx.x, lane = t & 63, wave = t >> 6;

    const float4* W4 = (const float4*)W;
    float4* Wl4 = (float4*)Wl;
    #pragma unroll
    for (int q = 0; q < 8; ++q) Wl4[t + q * 256] = W4[t + q * 256];

    int row0 = blockIdx.x * 16;                    // global row in [0, B*N)
    const float4* x4 = (const float4*)(x + (size_t)row0 * IND);
    float4* xl4 = (float4*)&xl[0][0];
    xl4[t] = x4[t];
    xl4[t + 256] = x4[t + 256];
    __syncthreads();

    float a1v = a[lane];
    float a2v = a[OUTD + lane];

    float acc[4] = {0.f, 0.f, 0.f, 0.f};
    int rbase = wave * 4;
    for (int k = 0; k < IND; k += 4) {
        float4 xv0 = *(const float4*)&xl[rbase + 0][k];
        float4 xv1 = *(const float4*)&xl[rbase + 1][k];
        float4 xv2 = *(const float4*)&xl[rbase + 2][k];
        float4 xv3 = *(const float4*)&xl[rbase + 3][k];
        #pragma unroll
        for (int q = 0; q < 4; ++q) {
            float w = Wl[(k + q) * OUTD + lane];
            acc[0] = fmaf(((const float*)&xv0)[q], w, acc[0]);
            acc[1] = fmaf(((const float*)&xv1)[q], w, acc[1]);
            acc[2] = fmaf(((const float*)&xv2)[q], w, acc[2]);
            acc[3] = fmaf(((const float*)&xv3)[q], w, acc[3]);
        }
    }
    #pragma unroll
    for (int rr = 0; rr < 4; ++rr) {
        size_t grow = (size_t)row0 + rbase + rr;
        tile[rbase + rr][lane] = acc[rr];
        float v1 = acc[rr] * a1v;
        float v2 = acc[rr] * a2v;
        #pragma unroll
        for (int o = 32; o; o >>= 1) {
            v1 += __shfl_xor(v1, o);
            v2 += __shfl_xor(v2, o);
        }
        if (lane == 0) { si[grow] = v1; sj[grow] = v2; }
    }
    __syncthreads();

    // transpose + bf16 hi/lo split: thread t -> d = t>>2, k-quad = (t&3)*4
    int d = t >> 2, kq = (t & 3) * 4;
    int b = row0 >> 11;                // batch
    int krow = (row0 & (NN - 1)) + kq; // k index within batch
    float v0 = tile[kq + 0][d], v1 = tile[kq + 1][d];
    float v2 = tile[kq + 2][d], v3 = tile[kq + 3][d];
    u32 b0 = __float_as_uint(v0), b1 = __float_as_uint(v1);
    u32 b2 = __float_as_uint(v2), b3 = __float_as_uint(v3);
    u32 h0 = b0 & 0xffff0000u, h1 = b1 & 0xffff0000u;
    u32 h2 = b2 & 0xffff0000u, h3 = b3 & 0xffff0000u;
    float l0 = v0 - __uint_as_float(h0), l1 = v1 - __uint_as_float(h1);
    float l2 = v2 - __uint_as_float(h2), l3 = v3 - __uint_as_float(h3);
    uint2 hi2, lo2;
    hi2.x = (b0 >> 16) | h1;
    hi2.y = (b2 >> 16) | h3;
    lo2.x = (__float_as_uint(l0) >> 16) | (__float_as_uint(l1) & 0xffff0000u);
    lo2.y = (__float_as_uint(l2) >> 16) | (__float_as_uint(l3) & 0xffff0000u);
    size_t off = ((size_t)b * OUTD + d) * NN + krow;   // in shorts (8B aligned)
    *(uint2*)(hT_hi + off) = hi2;
    *(uint2*)(hT_lo + off) = lo2;
}

// ---------------- K23: pipelined fused kernel --------------------------
// 512 blocks x 512 thr; block processes 2 tiles of 16 rows, prefetching
// tile t+1's adj into registers while tile t computes/writes.
// Per tile: mask+invS in registers -> 8 chunks of 256 j:
//   phase A: p computed once -> NT attn store + bf16 hi/lo to LDS
//   phase B: ds_read A-frags + global B-frags -> MFMA accumulate
// Barriers are LDS-only (no vmcnt drain -> stores never block).
__global__ __launch_bounds__(512, 2) void k23(const int* __restrict__ adj,
                                              const float* __restrict__ si,
                                              const float* __restrict__ sj,
                                              const short* __restrict__ hT_hi,
                                              const short* __restrict__ hT_lo,
                                              float* __restrict__ attn,
                                              float* __restrict__ hp) {
    __shared__ short p_hi[16][264];   // 8.25 KB (stride 264 breaks bank alias)
    __shared__ short p_lo[16][264];
    __shared__ f32x4 red[8][4][64];   // 32 KB

    int t = threadIdx.x, lane = t & 63, w = t >> 6;   // 8 waves
    int bk = blockIdx.x;
    int r0 = w * 2;
    int m = lane & 15, g = lane >> 4;

    int4 areg[2][8];   // this wave's 2 adj rows (prefetch buffer), 64 VGPR

    // prologue: load tile 0's adj
    {
        size_t grow = (size_t)(bk >> 7) * NN + (size_t)(bk & 127) * 16 + r0;
        const int4* a0 = (const int4*)(adj + grow * NN);
        const int4* a1 = (const int4*)(adj + (grow + 1) * NN);
        #pragma unroll
        for (int q = 0; q < 8; ++q) {
            areg[0][q] = a0[q * 64 + lane];
            areg[1][q] = a1[q * 64 + lane];
        }
    }

    for (int it = 0; it < 2; ++it) {
        int T = bk + it * NBLK;
        int b = T >> 7;
        int i0 = (T & 127) * 16;
        size_t rowbase = (size_t)b * NN + i0;
        const float* sjb = sj + (size_t)b * NN;
        const f32x4* sjb4 = (const f32x4*)sjb;

        // ---- mask + invS for this wave's 2 rows (consumes areg) ----
        u32 mask32[2];
        float inv[2], siv[2];
        #pragma unroll
        for (int r = 0; r < 2; ++r) {
            float s_i = si[rowbase + r0 + r];
            siv[r] = s_i;
            float sum = 0.f;
            u32 mk = 0;
            #pragma unroll
            for (int q = 0; q < 8; ++q) {
                f32x4 sv = sjb4[q * 64 + lane];
                int4 av = areg[r][q];
                float e, pe;
                e = s_i + sv.x; e = e > 0.f ? e : ALPHA * e; pe = __expf(e);
                if (av.x > 0) { mk |= 1u << (q * 4 + 0); sum += pe; }
                e = s_i + sv.y; e = e > 0.f ? e : ALPHA * e; pe = __expf(e);
                if (av.y > 0) { mk |= 1u << (q * 4 + 1); sum += pe; }
                e = s_i + sv.z; e = e > 0.f ? e : ALPHA * e; pe = __expf(e);
                if (av.z > 0) { mk |= 1u << (q * 4 + 2); sum += pe; }
                e = s_i + sv.w; e = e > 0.f ? e : ALPHA * e; pe = __expf(e);
                if (av.w > 0) { mk |= 1u << (q * 4 + 3); sum += pe; }
            }
            #pragma unroll
            for (int o = 32; o; o >>= 1) sum += __shfl_xor(sum, o);
            mask32[r] = mk;
            inv[r] = sum > 0.f ? 1.0f / sum : 0.f;
        }

        // ---- prefetch next tile's adj (overlaps all compute below) ----
        if (it == 0) {
            int T2 = bk + NBLK;
            size_t grow2 = (size_t)(T2 >> 7) * NN + (size_t)(T2 & 127) * 16 + r0;
            const int4* a0 = (const int4*)(adj + grow2 * NN);
            const int4* a1 = (const int4*)(adj + (grow2 + 1) * NN);
            #pragma unroll
            for (int q = 0; q < 8; ++q) {
                areg[0][q] = a0[q * 64 + lane];
                areg[1][q] = a1[q * 64 + lane];
            }
        }

        f32x4 acc[4];
        #pragma unroll
        for (int tt = 0; tt < 4; ++tt) acc[tt] = (f32x4){0.f, 0.f, 0.f, 0.f};

        const short* bh0 = hT_hi + ((size_t)b * OUTD + m) * NN;
        const short* bl0 = hT_lo + ((size_t)b * OUTD + m) * NN;

        for (int c = 0; c < 8; ++c) {
            // ---- phase A: compute p once; write attn + LDS bf16 frags ----
            f32x4 sv = sjb4[c * 64 + lane];
            #pragma unroll
            for (int r = 0; r < 2; ++r) {
                int row = r0 + r;
                u32 nib = (mask32[r] >> (c * 4)) & 0xFu;
                float s_i = siv[r], iv = inv[r];
                float e, p0, p1, p2, p3;
                e = s_i + sv.x; e = e > 0.f ? e : ALPHA * e;
                p0 = (nib & 1u) ? __expf(e) * iv : 0.f;
                e = s_i + sv.y; e = e > 0.f ? e : ALPHA * e;
                p1 = (nib & 2u) ? __expf(e) * iv : 0.f;
                e = s_i + sv.z; e = e > 0.f ? e : ALPHA * e;
                p2 = (nib & 4u) ? __expf(e) * iv : 0.f;
                e = s_i + sv.w; e = e > 0.f ? e : ALPHA * e;
                p3 = (nib & 8u) ? __expf(e) * iv : 0.f;

                f32x4 pv = {p0, p1, p2, p3};
                __builtin_nontemporal_store(pv,
                    (f32x4*)(attn + (rowbase + row) * (size_t)NN + c * 256 + lane * 4));

                u32 c0 = __float_as_uint(p0), c1 = __float_as_uint(p1);
                u32 c2 = __float_as_uint(p2), c3 = __float_as_uint(p3);
                u32 h0 = c0 & 0xffff0000u, h1 = c1 & 0xffff0000u;
                u32 h2 = c2 & 0xffff0000u, h3 = c3 & 0xffff0000u;
                float d0 = p0 - __uint_as_float(h0), d1 = p1 - __uint_as_float(h1);
                float d2 = p2 - __uint_as_float(h2), d3 = p3 - __uint_as_float(h3);
                uint2 hiw, low;
                hiw.x = (c0 >> 16) | h1;
                hiw.y = (c2 >> 16) | h3;
                low.x = (__float_as_uint(d0) >> 16) | (__float_as_uint(d1) & 0xffff0000u);
                low.y = (__float_as_uint(d2) >> 16) | (__float_as_uint(d3) & 0xffff0000u);
                *(uint2*)&p_hi[row][lane * 4] = hiw;
                *(uint2*)&p_lo[row][lane * 4] = low;
            }
            bar_lds();

            // ---- phase B: MFMA on this wave's k-slice (32 k of the 256) ----
            int kl = w * 32 + g * 8;          // local k in chunk
            int kk = c * 256 + kl;            // global k
            bf16x8 ph = *(const bf16x8*)&p_hi[m][kl];
            bf16x8 pl = *(const bf16x8*)&p_lo[m][kl];
            #pragma unroll
            for (int tt = 0; tt < 4; ++tt) {
                bf16x8 bh = *(const bf16x8*)(bh0 + (size_t)tt * 16 * NN + kk);
                bf16x8 bl = *(const bf16x8*)(bl0 + (size_t)tt * 16 * NN + kk);
                acc[tt] = __builtin_amdgcn_mfma_f32_16x16x32_bf16(ph, bh, acc[tt], 0, 0, 0);
                acc[tt] = __builtin_amdgcn_mfma_f32_16x16x32_bf16(ph, bl, acc[tt], 0, 0, 0);
                acc[tt] = __builtin_amdgcn_mfma_f32_16x16x32_bf16(pl, bh, acc[tt], 0, 0, 0);
            }
            bar_lds();
        }

        // ---- cross-wave reduce of D (16 rows x 64 dims) ----
        #pragma unroll
        for (int tt = 0; tt < 4; ++tt) red[w][tt][lane] = acc[tt];
        bar_lds();

        #pragma unroll
        for (int idx = t; idx < 16 * OUTD; idx += 512) {
            int row = idx >> 6, n = idx & 63;
            int ln = (row >> 2) * 16 + (n & 15);
            int reg = row & 3;
            float v = 0.f;
            #pragma unroll
            for (int ww = 0; ww < 8; ++ww)
                v += ((const float*)&red[ww][n >> 4][ln])[reg];
            hp[(rowbase + row) * OUTD + n] = v;
        }
        bar_lds();   // protect red/p_lds reuse by next tile
    }
}

extern "C" void kernel_launch(void* const* d_in, const int* in_sizes, int n_in,
                              void* d_out, int out_size, void* d_ws, size_t ws_size,
                              hipStream_t stream) {
    const float* x   = (const float*)d_in[0];
    const int*   adj = (const int*)d_in[1];
    const float* W   = (const float*)d_in[2];
    const float* a   = (const float*)d_in[3];

    float* out  = (float*)d_out;
    float* hp   = out;                                  // (B,N,OUT)
    float* attn = out + (size_t)BB * NN * OUTD;         // (B,N,N)

    char* ws = (char*)d_ws;
    short* hT_hi = (short*)ws;                           // 2 MB
    short* hT_lo = hT_hi + (size_t)BB * OUTD * NN;       // 2 MB
    float* si    = (float*)(hT_lo + (size_t)BB * OUTD * NN);
    float* sj    = si + (size_t)BB * NN;

    k1_hproj<<<BB * NN / 16, 256, 0, stream>>>(x, W, a, hT_hi, hT_lo, si, sj);
    k23<<<NBLK, 512, 0, stream>>>(adj, si, sj, hT_hi, hT_lo, attn, hp);
}